// Round 2
// baseline (78.339 us; speedup 1.0000x reference)
//
#include <hip/hip_runtime.h>
#include <math.h>

// Problem constants:
//   feature_map [B=2, H=38, W=38, C=512] float32 (NHWC, C contiguous)
//   rois        [B=2, N=64, 4] int32  (y, x, h, w), h,w >= P=7
//   out         [B, N, 7, 7, C] float32
#define RB 2
#define RN 64
#define RH 38
#define RW 38
#define RC 512
#define RP 7
#define NPIX (RH * RW)           // 1444 pixels per image
#define NCH 8                    // channels per block (one chunk)
#define GRAN (NPIX * 2)          // 16-B granules per 8-ch slice = 2888
#define LDS_SLOTS (GRAN + (GRAN >> 3) + 8)  // skewed layout
#define NTASK (16 * 49 * 2)      // 16 rois x 49 cells x 2 float4-quads = 1568

// LDS-staged ROI pooling.
//   Old scheme: 130 MB of scattered 1-KB reads through L2 (every pixel
//   re-read ~22x across overlapping ROIs), issued right after the harness's
//   268 MB poison fill whose writeback drain congests L2/HBM.
//   New scheme: block = (image, 8-channel chunk, roi-quarter). Stage the
//   image's 8-ch slice (46 KB) into LDS ONCE (global traffic -> ~6 MB HBM
//   compulsory), then all bin maxes read LDS (~52 TB/s aggregate).
//
// LDS layout: granule g = pixel*2 + quad (quad = which float4 of the 8 ch),
// stored at slot g + (g>>3) (skew breaks pixel-stride mod-8 bank aliasing
// for ds_read_b128). 52 KB LDS -> up to 3 blocks/CU; grid 512 = 2/CU avg,
// 8 waves/CU for LDS latency hiding on top of the depth-4 per-lane pipeline.
//
// XCD swizzle: blockIdx%8 -> XCD assumed; image 0 -> XCDs 0-3, image 1 ->
// XCDs 4-7 so stage reads stay in the local 4 MB L2s.
__device__ __forceinline__ float4 max4(float4 a, float4 b) {
  return make_float4(fmaxf(a.x, b.x), fmaxf(a.y, b.y),
                     fmaxf(a.z, b.z), fmaxf(a.w, b.w));
}

__global__ __launch_bounds__(256) void roi_pool_kernel(
    const float* __restrict__ fm, const int* __restrict__ rois,
    float* __restrict__ out) {
  __shared__ float4 lds[LDS_SLOTS];

  int bx = blockIdx.x;             // [0, 512)
  int xid = bx & 7;                // presumed XCD
  int j = bx >> 3;                 // [0, 64)
  int img = xid >> 2;              // 0..1
  int u = (xid & 3) | (j << 2);    // [0, 256), bijective
  int chunk = u & 63;              // 8-ch chunk [0, 64)
  int rq = u >> 6;                 // roi quarter [0, 4)

  const float* base = fm + (size_t)img * NPIX * RC + chunk * NCH;

  // ---- stage the 8-channel image slice into LDS (2888 x 16 B) ----
  {
    int s = threadIdx.x;
#pragma unroll
    for (int it = 0; it < 11; ++it) {
      int p = s >> 1, q = s & 1;
      float4 v = *(const float4*)(base + p * RC + (q << 2));
      lds[s + (s >> 3)] = v;
      s += 256;
    }
    if (s < GRAN) {
      int p = s >> 1, q = s & 1;
      float4 v = *(const float4*)(base + p * RC + (q << 2));
      lds[s + (s >> 3)] = v;
    }
  }
  __syncthreads();

  // ---- compute: 16 rois x 49 cells x 2 quads = 1568 tasks, 256 threads ----
  for (int it = 0; it < 7; ++it) {
    int t = threadIdx.x + (it << 8);
    bool valid = t < NTASK;
    int tc = valid ? t : (NTASK - 1);   // clamp: safe decode, store masked
    int ci = tc >> 1, q = tc & 1;
    int rl = ci / 49;                   // roi within quarter [0,16)
    int cir = ci - rl * 49;             // cell within roi [0,49)
    int py = cir / 7, px = cir - py * 7;
    int roi_g = (img << 6) | (rq << 4) | rl;
    const int4 rv = *(const int4*)(rois + (roi_g << 2));
    int y0 = rv.x, x0 = rv.y, h = rv.z, w = rv.w;

    // Bin [ys,ye) x [xs,xe); bins partition the ROI exactly (h,w >= 7).
    int ys = (py * h) / RP, ye = ((py + 1) * h) / RP;
    int xs = (px * w) / RP, xe = ((px + 1) * w) / RP;
    int bw = xe - xs;
    int cnt = bw * (ye - ys);           // 1..36 (bins <= 6x6)

    int g = (((y0 + ys) * RW + (x0 + xs)) << 1) | q;
    int gwrap = (RW - bw) << 1;

#define LD(dst) { dst = lds[g + (g >> 3)]; }
#define ADV() { g += 2; if (--xrem == 0) { xrem = bw; g += gwrap; } }

    float4 m = make_float4(-INFINITY, -INFINITY, -INFINITY, -INFINITY);
    int xrem = bw;
    // Depth-4 LDS pipeline; per-lane (divergent) counts are fine: finished
    // lanes get exec-masked, their a0..a3/m freeze until the epilogue.
    float4 a0, a1, a2, a3;
    LD(a0);
    if (cnt > 1) { ADV(); LD(a1); }
    if (cnt > 2) { ADV(); LD(a2); }
    if (cnt > 3) { ADV(); LD(a3); }
    int rem = cnt - 4;
    while (rem > 0) {
      m = max4(m, a0); ADV(); LD(a0); --rem;
      if (rem > 0) { m = max4(m, a1); ADV(); LD(a1); --rem; }
      if (rem > 0) { m = max4(m, a2); ADV(); LD(a2); --rem; }
      if (rem > 0) { m = max4(m, a3); ADV(); LD(a3); --rem; }
    }
    m = max4(m, a0);
    if (cnt > 1) m = max4(m, a1);
    if (cnt > 2) m = max4(m, a2);
    if (cnt > 3) m = max4(m, a3);
#undef LD
#undef ADV

    if (valid) {
      float4* o = (float4*)(out + (size_t)(roi_g * 49 + cir) * RC +
                            chunk * NCH) + q;
      *o = m;
    }
  }
}

extern "C" void kernel_launch(void* const* d_in, const int* in_sizes, int n_in,
                              void* d_out, int out_size, void* d_ws, size_t ws_size,
                              hipStream_t stream) {
  const float* fm = (const float*)d_in[0];
  const int* rois = (const int*)d_in[1];
  float* out = (float*)d_out;

  roi_pool_kernel<<<512, 256, 0, stream>>>(fm, rois, out);
}

// Round 3
// 68.186 us; speedup vs baseline: 1.1489x; 1.1489x over previous
//
#include <hip/hip_runtime.h>
#include <hip/hip_bf16.h>
#include <math.h>

// Problem constants:
//   feature_map [B=2, H=38, W=38, C=512] float32 (NHWC, C contiguous)
//   rois        [B=2, N=64, 4] int32  (y, x, h, w), h,w >= P
//   out         [B, N, P, P, C] float32, P = 7
#define RB 2
#define RN 64
#define RH 38
#define RW 38
#define RC 512
#define RP 7
#define CELLS (RB * RN * RP * RP)  // 6272
#define CPI (RN * RP * RP)         // cells per image = 3136
#define PPI (CPI / 2)              // cell-pairs per image = 1568

__device__ __forceinline__ float4 max4(float4 a, float4 b) {
  return make_float4(fmaxf(a.x, b.x), fmaxf(a.y, b.y), fmaxf(a.z, b.z),
                     fmaxf(a.w, b.w));
}

// One WAVE per (cell, channel-half): 64 lanes x 4 ch (1x float4) = 256 ch.
// 256-thread blocks -> 3136 blocks. Depth-4 software pipeline (4 loads in
// flight). ROI record fetched through the scalar path (index forced uniform
// via readfirstlane -> s_load_dwordx4) so bin math is scalar and the wave's
// roi->address dependency head is as short as possible.
//
// Measured ~5 us device time (dur_us 68.6 total, of which ~41 us is the
// harness's 256 MiB poison fill at 81% HBM and ~20 us is out-poison + tiny
// restore dispatches). LDS-staged variant (R2) regressed +9.5 us; depth-8 /
// decorrelated pairing (R1) were null -> this artifact is the best measured.
//
// XCD swizzle (round-robin blockIdx%8 -> XCD assumed): image 0 -> XCDs 0-3,
// image 1 -> XCDs 4-7; each ~3 MB image fits a 4 MB per-XCD L2.
__global__ __launch_bounds__(256) void roi_pool_kernel(
    const float* __restrict__ fm, const int* __restrict__ rois,
    float* __restrict__ out) {
  int wv = threadIdx.x >> 6;     // 0..3
  int lane = threadIdx.x & 63;
  int half = wv & 1;             // channel half: 0 -> ch[0,256), 1 -> [256,512)

  int bx = blockIdx.x;           // [0, 3136)
  int x = bx & 7;                // presumed XCD
  int j = bx >> 3;               // [0, 392)
  int img = x >> 2;              // 0..1
  int pair = img * PPI + ((j << 2) | (x & 3));  // bijective -> [0, 3136)
  int cell = pair * 2 + (wv >> 1);  // [0, 6272)

  int px = cell % RP;
  int t = cell / RP;
  int py = t % RP;
  t /= RP;                       // roi id = b*RN + n
  int b = t / RN;

  // Scalar-path roi fetch: uniform index -> SMEM load, scalar bin math.
  int rid = __builtin_amdgcn_readfirstlane(t);
  const int4 rv = *(const int4*)(rois + (rid << 2));
  int y0 = rv.x, x0 = rv.y, h = rv.z, w = rv.w;

  // Bin [ys,ye) x [xs,xe); bins partition the ROI exactly (h,w >= 7).
  int ys = (py * h) / RP, ye = ((py + 1) * h) / RP;
  int xs = (px * w) / RP, xe = ((px + 1) * w) / RP;
  int bw = xe - xs;
  int cnt = bw * (ye - ys);      // 1..36

  const float4* p =
      (const float4*)(fm +
                      (size_t)((b * RH + y0 + ys) * RW + x0 + xs) * RC) +
      (half << 6) + lane;
  const int pixstep = RC / 4;                  // 128 float4 per pixel
  const int wrapstep = (RW - bw) * (RC / 4);   // extra step at row wrap

#define STEP() \
  { p += pixstep; if (--xrem == 0) { xrem = bw; p += wrapstep; } }

  float4 m = make_float4(-INFINITY, -INFINITY, -INFINITY, -INFINITY);
  int xrem = bw;

  // Depth-4 pipeline. All branches wave-uniform (cnt/bw uniform per wave).
  float4 a0, a1, a2, a3;
  a0 = *p;
  if (cnt > 1) { STEP(); a1 = *p; }
  if (cnt > 2) { STEP(); a2 = *p; }
  if (cnt > 3) { STEP(); a3 = *p; }
  int rem = cnt - 4;
  while (rem > 0) {
    m = max4(m, a0);
    STEP(); a0 = *p; --rem;
    if (rem > 0) {
      m = max4(m, a1);
      STEP(); a1 = *p; --rem;
    }
    if (rem > 0) {
      m = max4(m, a2);
      STEP(); a2 = *p; --rem;
    }
    if (rem > 0) {
      m = max4(m, a3);
      STEP(); a3 = *p; --rem;
    }
  }
  m = max4(m, a0);
  if (cnt > 1) m = max4(m, a1);
  if (cnt > 2) m = max4(m, a2);
  if (cnt > 3) m = max4(m, a3);
#undef STEP

  // Normal (L2-cached) store: out is ~1.6 MB/XCD, L2 absorbs it faster than
  // NT writes pushed toward HBM.
  float4* o = (float4*)(out + (size_t)cell * RC) + (half << 6) + lane;
  *o = m;
}

extern "C" void kernel_launch(void* const* d_in, const int* in_sizes, int n_in,
                              void* d_out, int out_size, void* d_ws, size_t ws_size,
                              hipStream_t stream) {
  const float* fm = (const float*)d_in[0];
  const int* rois = (const int*)d_in[1];
  float* out = (float*)d_out;

  roi_pool_kernel<<<CELLS / 2, 256, 0, stream>>>(fm, rois, out);
}